// Round 2
// baseline (443.413 us; speedup 1.0000x reference)
//
#include <hip/hip_runtime.h>

#define NN 100000
#define EE 50000
#define GG (EE*4)   // owner groups (4 pairs each, same owner, same edge)

typedef __attribute__((ext_vector_type(8))) short bf16x8;
typedef __attribute__((ext_vector_type(4))) float f32x4;

__device__ __forceinline__ unsigned short f2bf(float f) {
  union { float f; unsigned int u; } c; c.f = f;
  unsigned int u = c.u;
  u = (u + 0x7fffu + ((u >> 16) & 1u)) >> 16;
  return (unsigned short)u;
}
__device__ __forceinline__ float bf2f(unsigned int lo16) {
  union { unsigned int u; float f; } c; c.u = lo16 << 16;
  return c.f;
}

struct __align__(8) us4 { unsigned short x, y, z, w; };

// ---------------- K0: combine weights on device (tiny) ----------------
__global__ void k_prep(const float* __restrict__ w_lin, const float* __restrict__ w_e,
                       const float* __restrict__ w_q, const float* __restrict__ b_q,
                       const float* __restrict__ w_k, const float* __restrict__ b_k,
                       const float* __restrict__ w_v, const float* __restrict__ b_v,
                       const float* __restrict__ w_o, const float* __restrict__ b_o,
                       unsigned short* __restrict__ WT, unsigned short* __restrict__ WeT,
                       unsigned short* __restrict__ WoT, float* __restrict__ bias384,
                       float* __restrict__ bkB, float* __restrict__ boB) {
  int t = blockIdx.x * 256 + threadIdx.x;
  if (t < 49152) {
    int n = t >> 7, k = t & 127;
    const float* wsel; int nn; float scale = 1.0f;
    if (n < 128)      { wsel = w_q; nn = n;       scale = 0.25f; }
    else if (n < 256) { wsel = w_k; nn = n - 128; }
    else              { wsel = w_v; nn = n - 256; }
    float s = 0.f;
    for (int d = 0; d < 128; ++d) s += w_lin[k*128 + d] * wsel[d*128 + nn];
    WT[n*128 + k] = f2bf(s * scale);
  } else if (t < 57344) {          // WeT: 128*64
    int i = t - 49152, n = i >> 6, k = i & 63;
    float s = 0.f;
    for (int d = 0; d < 128; ++d) s += w_e[k*128 + d] * w_k[d*128 + n];
    WeT[n*64 + k] = f2bf(s);
  } else if (t < 73728) {          // WoT: 128*128 transpose
    int i = t - 57344, n = i >> 7, k = i & 127;
    WoT[n*128 + k] = f2bf(w_o[k*128 + n]);
  } else if (t < 74112) {          // bias384 = [b_q/4, 0, b_v]
    int i = t - 73728;
    bias384[i] = (i < 128) ? b_q[i] * 0.25f : ((i < 256) ? 0.f : b_v[i - 256]);
  } else if (t < 74240) {
    bkB[t - 74112] = b_k[t - 74112];
  } else if (t < 74368) {
    boB[t - 74240] = b_o[t - 74240];
  }
}

// ---------------- K1: qkv = x @ WT^T + bias  (M=N, K=128, Ncols=384), bf16 out ----------------
__global__ __launch_bounds__(256) void k_qkv(const float* __restrict__ x,
                                             const unsigned short* __restrict__ WT,
                                             const float* __restrict__ bias,
                                             unsigned short* __restrict__ qkv) {
  __shared__ unsigned short As[64][136];
  __shared__ unsigned short Bs[64][136];
  int tid = threadIdx.x;
  int row0 = blockIdx.x * 64;
  int col0 = blockIdx.y * 64;
  #pragma unroll
  for (int it = 0; it < 8; ++it) {          // A: 64x128 f32 -> bf16
    int i4 = tid + it * 256;
    int r = i4 >> 5, c4 = i4 & 31;
    float4 vv = make_float4(0.f, 0.f, 0.f, 0.f);
    int gr = row0 + r;
    if (gr < NN) vv = *(const float4*)(x + (size_t)gr * 128 + c4 * 4);
    us4 s4 = { f2bf(vv.x), f2bf(vv.y), f2bf(vv.z), f2bf(vv.w) };
    *(us4*)(&As[r][c4 * 4]) = s4;
  }
  #pragma unroll
  for (int it = 0; it < 8; ++it) {          // B: rows col0..col0+63 of WT[384][128]
    int i4 = tid + it * 256;
    int r = i4 >> 5, c4 = i4 & 31;
    us4 s4 = *(const us4*)(WT + (size_t)(col0 + r) * 128 + c4 * 4);
    *(us4*)(&Bs[r][c4 * 4]) = s4;
  }
  __syncthreads();
  int w = tid >> 6, lane = tid & 63, lr = lane & 15, lk = lane >> 4;
  f32x4 acc[4] = {};
  #pragma unroll
  for (int kk = 0; kk < 4; ++kk) {
    int kof = kk * 32 + lk * 8;
    bf16x8 af = *(const bf16x8*)(&As[w * 16 + lr][kof]);
    #pragma unroll
    for (int nt = 0; nt < 4; ++nt) {
      bf16x8 bfrag = *(const bf16x8*)(&Bs[nt * 16 + lr][kof]);
      acc[nt] = __builtin_amdgcn_mfma_f32_16x16x32_bf16(af, bfrag, acc[nt], 0, 0, 0);
    }
  }
  #pragma unroll
  for (int nt = 0; nt < 4; ++nt) {
    int gcol = col0 + nt * 16 + lr;
    float b = bias[gcol];
    #pragma unroll
    for (int j = 0; j < 4; ++j) {
      int grow = row0 + w * 16 + lk * 4 + j;
      if (grow < NN) qkv[(size_t)grow * 384 + gcol] = f2bf(acc[nt][j] + b);
    }
  }
}

// ---------------- K2: Ke = edge_attr @ WeT^T + b_k  (M=E, K=64, Ncols=128), bf16 out ----------------
__global__ __launch_bounds__(256) void k_ke(const float* __restrict__ ea,
                                            const unsigned short* __restrict__ WeT,
                                            const float* __restrict__ bk,
                                            unsigned short* __restrict__ ke) {
  __shared__ unsigned short As[64][72];
  __shared__ unsigned short Bs[64][72];
  int tid = threadIdx.x;
  int row0 = blockIdx.x * 64;
  int col0 = blockIdx.y * 64;
  #pragma unroll
  for (int it = 0; it < 4; ++it) {
    int i4 = tid + it * 256;
    int r = i4 >> 4, c4 = i4 & 15;
    float4 vv = make_float4(0.f, 0.f, 0.f, 0.f);
    int gr = row0 + r;
    if (gr < EE) vv = *(const float4*)(ea + (size_t)gr * 64 + c4 * 4);
    us4 s4 = { f2bf(vv.x), f2bf(vv.y), f2bf(vv.z), f2bf(vv.w) };
    *(us4*)(&As[r][c4 * 4]) = s4;
  }
  #pragma unroll
  for (int it = 0; it < 4; ++it) {
    int i4 = tid + it * 256;
    int r = i4 >> 4, c4 = i4 & 15;
    us4 s4 = *(const us4*)(WeT + (size_t)(col0 + r) * 64 + c4 * 4);
    *(us4*)(&Bs[r][c4 * 4]) = s4;
  }
  __syncthreads();
  int w = tid >> 6, lane = tid & 63, lr = lane & 15, lk = lane >> 4;
  f32x4 acc[4] = {};
  #pragma unroll
  for (int kk = 0; kk < 2; ++kk) {
    int kof = kk * 32 + lk * 8;
    bf16x8 af = *(const bf16x8*)(&As[w * 16 + lr][kof]);
    #pragma unroll
    for (int nt = 0; nt < 4; ++nt) {
      bf16x8 bfrag = *(const bf16x8*)(&Bs[nt * 16 + lr][kof]);
      acc[nt] = __builtin_amdgcn_mfma_f32_16x16x32_bf16(af, bfrag, acc[nt], 0, 0, 0);
    }
  }
  #pragma unroll
  for (int nt = 0; nt < 4; ++nt) {
    int gcol = col0 + nt * 16 + lr;
    float b = bk[gcol];
    #pragma unroll
    for (int j = 0; j < 4; ++j) {
      int grow = row0 + w * 16 + lk * 4 + j;
      if (grow < EE) ke[(size_t)grow * 128 + gcol] = f2bf(acc[nt][j] + b);
    }
  }
}

// ---------------- CSR build: count -> scan -> scatter ----------------
__global__ void k_count(const int* __restrict__ owners, int* __restrict__ counts) {
  int g = blockIdx.x * 256 + threadIdx.x;
  if (g < GG) atomicAdd(counts + owners[(size_t)g * 4], 1);
}

__global__ __launch_bounds__(256) void k_scan(const int* __restrict__ counts,
                                              int* __restrict__ starts,
                                              int* __restrict__ wcursor) {
  __shared__ int tsum[256];
  int tid = threadIdx.x;
  const int CH = (NN + 255) / 256;                // 391
  int lo = tid * CH, hi = lo + CH; if (hi > NN) hi = NN;
  int s = 0;
  for (int i = lo; i < hi; ++i) s += counts[i];
  tsum[tid] = s;
  __syncthreads();
  if (tid == 0) {
    int acc = 0;
    for (int i = 0; i < 256; ++i) { int t = tsum[i]; tsum[i] = acc; acc += t; }
  }
  __syncthreads();
  int acc = tsum[tid];
  for (int i = lo; i < hi; ++i) {
    starts[i] = acc; wcursor[i] = acc; acc += counts[i];
  }
  if (tid == 255) starts[NN] = acc;
}

__global__ void k_scatter(const int* __restrict__ owners, int* __restrict__ wcursor,
                          int* __restrict__ glist) {
  int g = blockIdx.x * 256 + threadIdx.x;
  if (g < GG) {
    int v = owners[(size_t)g * 4];
    int pos = atomicAdd(wcursor + v, 1);
    glist[pos] = g;
  }
}

// ---------------- K3: per-node pair pass, no atomics, bf16 ctx out ----------------
// One wave per node: loop its groups, accumulate exp/denom/ctx in registers,
// normalize in-register, single bf16 row write.
__global__ __launch_bounds__(256) void k_pair_csr(const unsigned short* __restrict__ qkv,
                                                  const unsigned short* __restrict__ ke,
                                                  const int* __restrict__ starts,
                                                  const int* __restrict__ glist,
                                                  const int* __restrict__ pair_u,
                                                  unsigned short* __restrict__ ctxb) {
  int v = blockIdx.x * 4 + (threadIdx.x >> 6);
  if (v >= NN) return;
  int lane = threadIdx.x & 63;
  unsigned int qw = *(const unsigned int*)(qkv + (size_t)v * 384 + 2 * lane);
  float q0 = bf2f(qw & 0xffffu), q1 = bf2f(qw >> 16);
  int s = starts[v], epos = starts[v + 1];
  float c0 = 0.f, c1 = 0.f, dsum = 0.f;
  for (int i = s; i < epos; ++i) {
    int g = __builtin_amdgcn_readfirstlane(glist[i]);
    int e = g >> 2;
    int p0 = g * 4;
    unsigned int kew = *(const unsigned int*)(ke + (size_t)e * 128 + 2 * lane);
    float e0 = bf2f(kew & 0xffffu), e1 = bf2f(kew >> 16);
    #pragma unroll
    for (int j = 0; j < 4; ++j) {
      int u = __builtin_amdgcn_readfirstlane(pair_u[p0 + j]);
      unsigned int kw = *(const unsigned int*)(qkv + (size_t)u * 384 + 128 + 2 * lane);
      float sc = q0 * (bf2f(kw & 0xffffu) + e0) + q1 * (bf2f(kw >> 16) + e1);
      sc += __shfl_xor(sc, 1);
      sc += __shfl_xor(sc, 2);
      sc += __shfl_xor(sc, 4);                     // head-local sum (8 lanes/head)
      float ex = __expf(sc);                       // |scores| small: no max-sub pass
      unsigned int vw = *(const unsigned int*)(qkv + (size_t)u * 384 + 256 + 2 * lane);
      c0 += ex * bf2f(vw & 0xffffu);
      c1 += ex * bf2f(vw >> 16);
      dsum += ex;
    }
  }
  float inv = dsum > 0.f ? 1.0f / dsum : 0.f;
  unsigned int packed = (unsigned int)f2bf(c0 * inv) | ((unsigned int)f2bf(c1 * inv) << 16);
  *(unsigned int*)(ctxb + (size_t)v * 128 + 2 * lane) = packed;
}

// ---------------- K5: out = relu( ctxb @ WoT^T + b_o ), f32 out ----------------
__global__ __launch_bounds__(256) void k_out(const unsigned short* __restrict__ ctxb,
                                             const unsigned short* __restrict__ WoT,
                                             const float* __restrict__ bo,
                                             float* __restrict__ out) {
  __shared__ unsigned short As[64][136];
  __shared__ unsigned short Bs[128][136];
  int tid = threadIdx.x;
  int row0 = blockIdx.x * 64;
  #pragma unroll
  for (int it = 0; it < 8; ++it) {          // A: bf16 ctx rows direct
    int i4 = tid + it * 256;
    int r = i4 >> 5, c4 = i4 & 31;
    int gr = row0 + r;
    us4 s4 = { 0, 0, 0, 0 };
    if (gr < NN) s4 = *(const us4*)(ctxb + (size_t)gr * 128 + c4 * 4);
    *(us4*)(&As[r][c4 * 4]) = s4;
  }
  #pragma unroll
  for (int it = 0; it < 16; ++it) {         // B: whole WoT[128][128]
    int i4 = tid + it * 256;
    int r = i4 >> 5, c4 = i4 & 31;
    *(us4*)(&Bs[r][c4 * 4]) = *(const us4*)(WoT + (size_t)r * 128 + c4 * 4);
  }
  __syncthreads();
  int w = tid >> 6, lane = tid & 63, lr = lane & 15, lk = lane >> 4;
  f32x4 acc[8] = {};
  #pragma unroll
  for (int kk = 0; kk < 4; ++kk) {
    int kof = kk * 32 + lk * 8;
    bf16x8 af = *(const bf16x8*)(&As[w * 16 + lr][kof]);
    #pragma unroll
    for (int nt = 0; nt < 8; ++nt) {
      bf16x8 bfrag = *(const bf16x8*)(&Bs[nt * 16 + lr][kof]);
      acc[nt] = __builtin_amdgcn_mfma_f32_16x16x32_bf16(af, bfrag, acc[nt], 0, 0, 0);
    }
  }
  #pragma unroll
  for (int nt = 0; nt < 8; ++nt) {
    int gcol = nt * 16 + lr;
    float b = bo[gcol];
    #pragma unroll
    for (int j = 0; j < 4; ++j) {
      int grow = row0 + w * 16 + lk * 4 + j;
      if (grow < NN) {
        float vvv = acc[nt][j] + b;
        out[(size_t)grow * 128 + gcol] = vvv > 0.f ? vvv : 0.f;
      }
    }
  }
}

extern "C" void kernel_launch(void* const* d_in, const int* in_sizes, int n_in,
                              void* d_out, int out_size, void* d_ws, size_t ws_size,
                              hipStream_t stream) {
  const float* x      = (const float*)d_in[0];
  const float* ea     = (const float*)d_in[1];
  const float* w_lin  = (const float*)d_in[2];
  const float* w_e    = (const float*)d_in[3];
  const float* w_q    = (const float*)d_in[4];
  const float* b_q    = (const float*)d_in[5];
  const float* w_k    = (const float*)d_in[6];
  const float* b_k    = (const float*)d_in[7];
  const float* w_v    = (const float*)d_in[8];
  const float* b_v    = (const float*)d_in[9];
  const float* w_o    = (const float*)d_in[10];
  const float* b_o    = (const float*)d_in[11];
  const int* owners   = (const int*)d_in[12];
  const int* pair_u   = (const int*)d_in[14];
  float* out = (float*)d_out;

  char* base = (char*)d_ws;
  size_t o = 0;
  auto alloc = [&](size_t b) {
    void* p = base + o;
    o = (o + b + 255) & ~(size_t)255;
    return p;
  };
  unsigned short* WT      = (unsigned short*)alloc((size_t)384 * 128 * 2);
  unsigned short* WeT     = (unsigned short*)alloc((size_t)128 * 64 * 2);
  unsigned short* WoT     = (unsigned short*)alloc((size_t)128 * 128 * 2);
  float* bias384          = (float*)alloc(384 * 4);
  float* bkB              = (float*)alloc(128 * 4);
  float* boB              = (float*)alloc(128 * 4);
  unsigned short* qkv     = (unsigned short*)alloc((size_t)NN * 384 * 2);
  unsigned short* keb     = (unsigned short*)alloc((size_t)EE * 128 * 2);
  unsigned short* ctxb    = (unsigned short*)alloc((size_t)NN * 128 * 2);
  int* counts             = (int*)alloc((size_t)NN * 4);
  int* starts             = (int*)alloc((size_t)(NN + 1) * 4);
  int* wcursor            = (int*)alloc((size_t)NN * 4);
  int* glist              = (int*)alloc((size_t)GG * 4);

  hipMemsetAsync(counts, 0, (size_t)NN * 4, stream);

  k_prep<<<291, 256, 0, stream>>>(w_lin, w_e, w_q, b_q, w_k, b_k, w_v, b_v, w_o, b_o,
                                  WT, WeT, WoT, bias384, bkB, boB);
  k_qkv<<<dim3(1563, 6), 256, 0, stream>>>(x, WT, bias384, qkv);
  k_ke<<<dim3(782, 2), 256, 0, stream>>>(ea, WeT, bkB, keb);
  k_count<<<782, 256, 0, stream>>>(owners, counts);
  k_scan<<<1, 256, 0, stream>>>(counts, starts, wcursor);
  k_scatter<<<782, 256, 0, stream>>>(owners, wcursor, glist);
  k_pair_csr<<<25000, 256, 0, stream>>>(qkv, keb, starts, glist, pair_u, ctxb);
  k_out<<<1563, 256, 0, stream>>>(ctxb, WoT, boB, out);
}

// Round 3
// 201.378 us; speedup vs baseline: 2.2019x; 2.2019x over previous
//
#include <hip/hip_runtime.h>

#define NN 100000
#define EE 50000
#define GG (EE*4)   // owner groups (4 pairs each, same owner, same edge)
#define NB 391      // ceil(NN/256)

typedef __attribute__((ext_vector_type(8))) short bf16x8;
typedef __attribute__((ext_vector_type(4))) float f32x4;

__device__ __forceinline__ unsigned short f2bf(float f) {
  union { float f; unsigned int u; } c; c.f = f;
  unsigned int u = c.u;
  u = (u + 0x7fffu + ((u >> 16) & 1u)) >> 16;
  return (unsigned short)u;
}
__device__ __forceinline__ float bf2f(unsigned int lo16) {
  union { unsigned int u; float f; } c; c.u = lo16 << 16;
  return c.f;
}

struct __align__(8) us4 { unsigned short x, y, z, w; };

// ---------------- K0: combine weights on device (tiny) ----------------
__global__ void k_prep(const float* __restrict__ w_lin, const float* __restrict__ w_e,
                       const float* __restrict__ w_q, const float* __restrict__ b_q,
                       const float* __restrict__ w_k, const float* __restrict__ b_k,
                       const float* __restrict__ w_v, const float* __restrict__ b_v,
                       const float* __restrict__ w_o, const float* __restrict__ b_o,
                       unsigned short* __restrict__ WT, unsigned short* __restrict__ WeT,
                       unsigned short* __restrict__ WoT, float* __restrict__ bias384,
                       float* __restrict__ bkB, float* __restrict__ boB) {
  int t = blockIdx.x * 256 + threadIdx.x;
  if (t < 49152) {
    int n = t >> 7, k = t & 127;
    const float* wsel; int nn; float scale = 1.0f;
    if (n < 128)      { wsel = w_q; nn = n;       scale = 0.25f; }
    else if (n < 256) { wsel = w_k; nn = n - 128; }
    else              { wsel = w_v; nn = n - 256; }
    float s = 0.f;
    for (int d = 0; d < 128; ++d) s += w_lin[k*128 + d] * wsel[d*128 + nn];
    WT[n*128 + k] = f2bf(s * scale);
  } else if (t < 57344) {          // WeT: 128*64
    int i = t - 49152, n = i >> 6, k = i & 63;
    float s = 0.f;
    for (int d = 0; d < 128; ++d) s += w_e[k*128 + d] * w_k[d*128 + n];
    WeT[n*64 + k] = f2bf(s);
  } else if (t < 73728) {          // WoT: 128*128 transpose
    int i = t - 57344, n = i >> 7, k = i & 127;
    WoT[n*128 + k] = f2bf(w_o[k*128 + n]);
  } else if (t < 74112) {          // bias384 = [b_q/4, 0, b_v]
    int i = t - 73728;
    bias384[i] = (i < 128) ? b_q[i] * 0.25f : ((i < 256) ? 0.f : b_v[i - 256]);
  } else if (t < 74240) {
    bkB[t - 74112] = b_k[t - 74112];
  } else if (t < 74368) {
    boB[t - 74240] = b_o[t - 74240];
  }
}

// ---------------- K1: qkv = x @ WT^T + bias  (M=N, K=128, Ncols=384), bf16 out ----------------
// One block per 64-row tile; loops all 6 column tiles reusing the staged A tile.
__global__ __launch_bounds__(256) void k_qkv(const float* __restrict__ x,
                                             const unsigned short* __restrict__ WT,
                                             const float* __restrict__ bias,
                                             unsigned short* __restrict__ qkv) {
  __shared__ unsigned short As[64][136];
  __shared__ unsigned short Bs[64][136];
  int tid = threadIdx.x;
  int row0 = blockIdx.x * 64;
  #pragma unroll
  for (int it = 0; it < 8; ++it) {          // A: 64x128 f32 -> bf16, staged once
    int i4 = tid + it * 256;
    int r = i4 >> 5, c4 = i4 & 31;
    float4 vv = make_float4(0.f, 0.f, 0.f, 0.f);
    int gr = row0 + r;
    if (gr < NN) vv = *(const float4*)(x + (size_t)gr * 128 + c4 * 4);
    us4 s4 = { f2bf(vv.x), f2bf(vv.y), f2bf(vv.z), f2bf(vv.w) };
    *(us4*)(&As[r][c4 * 4]) = s4;
  }
  int w = tid >> 6, lane = tid & 63, lr = lane & 15, lk = lane >> 4;
  for (int yb = 0; yb < 6; ++yb) {
    int col0 = yb * 64;
    __syncthreads();                        // prev MFMA done (and As staged, first iter)
    #pragma unroll
    for (int it = 0; it < 8; ++it) {        // B: rows col0..col0+63 of WT[384][128]
      int i4 = tid + it * 256;
      int r = i4 >> 5, c4 = i4 & 31;
      *(us4*)(&Bs[r][c4 * 4]) = *(const us4*)(WT + (size_t)(col0 + r) * 128 + c4 * 4);
    }
    __syncthreads();
    f32x4 acc[4] = {};
    #pragma unroll
    for (int kk = 0; kk < 4; ++kk) {
      int kof = kk * 32 + lk * 8;
      bf16x8 af = *(const bf16x8*)(&As[w * 16 + lr][kof]);
      #pragma unroll
      for (int nt = 0; nt < 4; ++nt) {
        bf16x8 bfrag = *(const bf16x8*)(&Bs[nt * 16 + lr][kof]);
        acc[nt] = __builtin_amdgcn_mfma_f32_16x16x32_bf16(af, bfrag, acc[nt], 0, 0, 0);
      }
    }
    #pragma unroll
    for (int nt = 0; nt < 4; ++nt) {
      int gcol = col0 + nt * 16 + lr;
      float b = bias[gcol];
      #pragma unroll
      for (int j = 0; j < 4; ++j) {
        int grow = row0 + w * 16 + lk * 4 + j;
        if (grow < NN) qkv[(size_t)grow * 384 + gcol] = f2bf(acc[nt][j] + b);
      }
    }
  }
}

// ---------------- K2: Ke = edge_attr @ WeT^T + b_k  (M=E, K=64, Ncols=128), bf16 out ----------------
__global__ __launch_bounds__(256) void k_ke(const float* __restrict__ ea,
                                            const unsigned short* __restrict__ WeT,
                                            const float* __restrict__ bk,
                                            unsigned short* __restrict__ ke) {
  __shared__ unsigned short As[64][72];
  __shared__ unsigned short Bs[64][72];
  int tid = threadIdx.x;
  int row0 = blockIdx.x * 64;
  int col0 = blockIdx.y * 64;
  #pragma unroll
  for (int it = 0; it < 4; ++it) {
    int i4 = tid + it * 256;
    int r = i4 >> 4, c4 = i4 & 15;
    float4 vv = make_float4(0.f, 0.f, 0.f, 0.f);
    int gr = row0 + r;
    if (gr < EE) vv = *(const float4*)(ea + (size_t)gr * 64 + c4 * 4);
    us4 s4 = { f2bf(vv.x), f2bf(vv.y), f2bf(vv.z), f2bf(vv.w) };
    *(us4*)(&As[r][c4 * 4]) = s4;
  }
  #pragma unroll
  for (int it = 0; it < 4; ++it) {
    int i4 = tid + it * 256;
    int r = i4 >> 4, c4 = i4 & 15;
    us4 s4 = *(const us4*)(WeT + (size_t)(col0 + r) * 64 + c4 * 4);
    *(us4*)(&Bs[r][c4 * 4]) = s4;
  }
  __syncthreads();
  int w = tid >> 6, lane = tid & 63, lr = lane & 15, lk = lane >> 4;
  f32x4 acc[4] = {};
  #pragma unroll
  for (int kk = 0; kk < 2; ++kk) {
    int kof = kk * 32 + lk * 8;
    bf16x8 af = *(const bf16x8*)(&As[w * 16 + lr][kof]);
    #pragma unroll
    for (int nt = 0; nt < 4; ++nt) {
      bf16x8 bfrag = *(const bf16x8*)(&Bs[nt * 16 + lr][kof]);
      acc[nt] = __builtin_amdgcn_mfma_f32_16x16x32_bf16(af, bfrag, acc[nt], 0, 0, 0);
    }
  }
  #pragma unroll
  for (int nt = 0; nt < 4; ++nt) {
    int gcol = col0 + nt * 16 + lr;
    float b = bk[gcol];
    #pragma unroll
    for (int j = 0; j < 4; ++j) {
      int grow = row0 + w * 16 + lk * 4 + j;
      if (grow < EE) ke[(size_t)grow * 128 + gcol] = f2bf(acc[nt][j] + b);
    }
  }
}

// ---------------- CSR build: count -> parallel scan (3 kernels) -> scatter ----------------
__global__ void k_count(const int* __restrict__ owners, int* __restrict__ counts) {
  int g = blockIdx.x * 256 + threadIdx.x;
  if (g < GG) atomicAdd(counts + owners[(size_t)g * 4], 1);
}

// per-block exclusive scan of 256 counts; block sum out
__global__ __launch_bounds__(256) void k_scan1(const int* __restrict__ counts,
                                               int* __restrict__ lofs,
                                               int* __restrict__ bsums) {
  __shared__ int tmp[256];
  int tid = threadIdx.x;
  int i = blockIdx.x * 256 + tid;
  int v = (i < NN) ? counts[i] : 0;
  tmp[tid] = v;
  __syncthreads();
  int val = v;
  #pragma unroll
  for (int off = 1; off < 256; off <<= 1) {
    int t = (tid >= off) ? tmp[tid - off] : 0;
    __syncthreads();
    val += t;
    tmp[tid] = val;
    __syncthreads();
  }
  if (i < NN) lofs[i] = val - v;            // exclusive within block
  if (tid == 255) bsums[blockIdx.x] = val;  // block total
}

// single-block exclusive scan of NB block sums (in-place)
__global__ __launch_bounds__(512) void k_scan2(int* __restrict__ bsums) {
  __shared__ int tmp[512];
  int tid = threadIdx.x;
  int v = (tid < NB) ? bsums[tid] : 0;
  tmp[tid] = v;
  __syncthreads();
  int val = v;
  #pragma unroll
  for (int off = 1; off < 512; off <<= 1) {
    int t = (tid >= off) ? tmp[tid - off] : 0;
    __syncthreads();
    val += t;
    tmp[tid] = val;
    __syncthreads();
  }
  if (tid < NB) bsums[tid] = val - v;       // exclusive
}

__global__ void k_scan3(const int* __restrict__ lofs, const int* __restrict__ bsums,
                        int* __restrict__ starts, int* __restrict__ wcursor) {
  int i = blockIdx.x * 256 + threadIdx.x;
  if (i < NN) {
    int s = lofs[i] + bsums[i >> 8];
    starts[i] = s;
    wcursor[i] = s;
  }
  if (i == 0) starts[NN] = GG;              // total is always GG (one owner per group)
}

__global__ void k_scatter(const int* __restrict__ owners, int* __restrict__ wcursor,
                          int* __restrict__ glist) {
  int g = blockIdx.x * 256 + threadIdx.x;
  if (g < GG) {
    int v = owners[(size_t)g * 4];
    int pos = atomicAdd(wcursor + v, 1);
    glist[pos] = g;
  }
}

// ---------------- K3: per-node pair pass, no atomics, bf16 ctx out ----------------
__global__ __launch_bounds__(256) void k_pair_csr(const unsigned short* __restrict__ qkv,
                                                  const unsigned short* __restrict__ ke,
                                                  const int* __restrict__ starts,
                                                  const int* __restrict__ glist,
                                                  const int* __restrict__ pair_u,
                                                  unsigned short* __restrict__ ctxb) {
  int v = blockIdx.x * 4 + (threadIdx.x >> 6);
  if (v >= NN) return;
  int lane = threadIdx.x & 63;
  unsigned int qw = *(const unsigned int*)(qkv + (size_t)v * 384 + 2 * lane);
  float q0 = bf2f(qw & 0xffffu), q1 = bf2f(qw >> 16);
  int s = starts[v], epos = starts[v + 1];
  float c0 = 0.f, c1 = 0.f, dsum = 0.f;
  for (int i = s; i < epos; ++i) {
    int g = __builtin_amdgcn_readfirstlane(glist[i]);
    int e = g >> 2;
    int p0 = g * 4;
    unsigned int kew = *(const unsigned int*)(ke + (size_t)e * 128 + 2 * lane);
    float e0 = bf2f(kew & 0xffffu), e1 = bf2f(kew >> 16);
    #pragma unroll
    for (int j = 0; j < 4; ++j) {
      int u = __builtin_amdgcn_readfirstlane(pair_u[p0 + j]);
      unsigned int kw = *(const unsigned int*)(qkv + (size_t)u * 384 + 128 + 2 * lane);
      float sc = q0 * (bf2f(kw & 0xffffu) + e0) + q1 * (bf2f(kw >> 16) + e1);
      sc += __shfl_xor(sc, 1);
      sc += __shfl_xor(sc, 2);
      sc += __shfl_xor(sc, 4);                     // head-local sum (8 lanes/head)
      float ex = __expf(sc);                       // |scores| small: no max-sub pass
      unsigned int vw = *(const unsigned int*)(qkv + (size_t)u * 384 + 256 + 2 * lane);
      c0 += ex * bf2f(vw & 0xffffu);
      c1 += ex * bf2f(vw >> 16);
      dsum += ex;
    }
  }
  float inv = dsum > 0.f ? 1.0f / dsum : 0.f;
  unsigned int packed = (unsigned int)f2bf(c0 * inv) | ((unsigned int)f2bf(c1 * inv) << 16);
  *(unsigned int*)(ctxb + (size_t)v * 128 + 2 * lane) = packed;
}

// ---------------- K5: out = relu( ctxb @ WoT^T + b_o ), f32 out ----------------
__global__ __launch_bounds__(256) void k_out(const unsigned short* __restrict__ ctxb,
                                             const unsigned short* __restrict__ WoT,
                                             const float* __restrict__ bo,
                                             float* __restrict__ out) {
  __shared__ unsigned short As[64][136];
  __shared__ unsigned short Bs[128][136];
  int tid = threadIdx.x;
  int row0 = blockIdx.x * 64;
  #pragma unroll
  for (int it = 0; it < 8; ++it) {
    int i4 = tid + it * 256;
    int r = i4 >> 5, c4 = i4 & 31;
    int gr = row0 + r;
    us4 s4 = { 0, 0, 0, 0 };
    if (gr < NN) s4 = *(const us4*)(ctxb + (size_t)gr * 128 + c4 * 4);
    *(us4*)(&As[r][c4 * 4]) = s4;
  }
  #pragma unroll
  for (int it = 0; it < 16; ++it) {
    int i4 = tid + it * 256;
    int r = i4 >> 5, c4 = i4 & 31;
    *(us4*)(&Bs[r][c4 * 4]) = *(const us4*)(WoT + (size_t)r * 128 + c4 * 4);
  }
  __syncthreads();
  int w = tid >> 6, lane = tid & 63, lr = lane & 15, lk = lane >> 4;
  f32x4 acc[8] = {};
  #pragma unroll
  for (int kk = 0; kk < 4; ++kk) {
    int kof = kk * 32 + lk * 8;
    bf16x8 af = *(const bf16x8*)(&As[w * 16 + lr][kof]);
    #pragma unroll
    for (int nt = 0; nt < 8; ++nt) {
      bf16x8 bfrag = *(const bf16x8*)(&Bs[nt * 16 + lr][kof]);
      acc[nt] = __builtin_amdgcn_mfma_f32_16x16x32_bf16(af, bfrag, acc[nt], 0, 0, 0);
    }
  }
  #pragma unroll
  for (int nt = 0; nt < 8; ++nt) {
    int gcol = nt * 16 + lr;
    float b = bo[gcol];
    #pragma unroll
    for (int j = 0; j < 4; ++j) {
      int grow = row0 + w * 16 + lk * 4 + j;
      if (grow < NN) {
        float vvv = acc[nt][j] + b;
        out[(size_t)grow * 128 + gcol] = vvv > 0.f ? vvv : 0.f;
      }
    }
  }
}

extern "C" void kernel_launch(void* const* d_in, const int* in_sizes, int n_in,
                              void* d_out, int out_size, void* d_ws, size_t ws_size,
                              hipStream_t stream) {
  const float* x      = (const float*)d_in[0];
  const float* ea     = (const float*)d_in[1];
  const float* w_lin  = (const float*)d_in[2];
  const float* w_e    = (const float*)d_in[3];
  const float* w_q    = (const float*)d_in[4];
  const float* b_q    = (const float*)d_in[5];
  const float* w_k    = (const float*)d_in[6];
  const float* b_k    = (const float*)d_in[7];
  const float* w_v    = (const float*)d_in[8];
  const float* b_v    = (const float*)d_in[9];
  const float* w_o    = (const float*)d_in[10];
  const float* b_o    = (const float*)d_in[11];
  const int* owners   = (const int*)d_in[12];
  const int* pair_u   = (const int*)d_in[14];
  float* out = (float*)d_out;

  char* base = (char*)d_ws;
  size_t o = 0;
  auto alloc = [&](size_t b) {
    void* p = base + o;
    o = (o + b + 255) & ~(size_t)255;
    return p;
  };
  unsigned short* WT      = (unsigned short*)alloc((size_t)384 * 128 * 2);
  unsigned short* WeT     = (unsigned short*)alloc((size_t)128 * 64 * 2);
  unsigned short* WoT     = (unsigned short*)alloc((size_t)128 * 128 * 2);
  float* bias384          = (float*)alloc(384 * 4);
  float* bkB              = (float*)alloc(128 * 4);
  float* boB              = (float*)alloc(128 * 4);
  unsigned short* qkv     = (unsigned short*)alloc((size_t)NN * 384 * 2);
  unsigned short* keb     = (unsigned short*)alloc((size_t)EE * 128 * 2);
  unsigned short* ctxb    = (unsigned short*)alloc((size_t)NN * 128 * 2);
  int* counts             = (int*)alloc((size_t)NN * 4);
  int* starts             = (int*)alloc((size_t)(NN + 1) * 4);
  int* wcursor            = (int*)alloc((size_t)NN * 4);
  int* glist              = (int*)alloc((size_t)GG * 4);
  int* lofs               = (int*)alloc((size_t)NN * 4);
  int* bsums              = (int*)alloc((size_t)NB * 4);

  hipMemsetAsync(counts, 0, (size_t)NN * 4, stream);

  k_prep<<<291, 256, 0, stream>>>(w_lin, w_e, w_q, b_q, w_k, b_k, w_v, b_v, w_o, b_o,
                                  WT, WeT, WoT, bias384, bkB, boB);
  k_qkv<<<1563, 256, 0, stream>>>(x, WT, bias384, qkv);
  k_ke<<<dim3(782, 2), 256, 0, stream>>>(ea, WeT, bkB, keb);
  k_count<<<782, 256, 0, stream>>>(owners, counts);
  k_scan1<<<NB, 256, 0, stream>>>(counts, lofs, bsums);
  k_scan2<<<1, 512, 0, stream>>>(bsums);
  k_scan3<<<NB, 256, 0, stream>>>(lofs, bsums, starts, wcursor);
  k_scatter<<<782, 256, 0, stream>>>(owners, wcursor, glist);
  k_pair_csr<<<25000, 256, 0, stream>>>(qkv, keb, starts, glist, pair_u, ctxb);
  k_out<<<1563, 256, 0, stream>>>(ctxb, WoT, boB, out);
}

// Round 4
// 193.111 us; speedup vs baseline: 2.2962x; 1.0428x over previous
//
#include <hip/hip_runtime.h>

#define NN 100000
#define EE 50000
#define GG (EE*4)   // owner groups (4 pairs each, same owner, same edge)
#define NB 391      // ceil(NN/256)

typedef __attribute__((ext_vector_type(8))) short bf16x8;
typedef __attribute__((ext_vector_type(4))) float f32x4;

__device__ __forceinline__ unsigned short f2bf(float f) {
  union { float f; unsigned int u; } c; c.f = f;
  unsigned int u = c.u;
  u = (u + 0x7fffu + ((u >> 16) & 1u)) >> 16;
  return (unsigned short)u;
}
__device__ __forceinline__ float bf2f(unsigned int lo16) {
  union { unsigned int u; float f; } c; c.u = lo16 << 16;
  return c.f;
}

struct __align__(8) us4 { unsigned short x, y, z, w; };

// ---------------- K0: combine weights on device (tiny) ----------------
__global__ void k_prep(const float* __restrict__ w_lin, const float* __restrict__ w_e,
                       const float* __restrict__ w_q, const float* __restrict__ b_q,
                       const float* __restrict__ w_k, const float* __restrict__ b_k,
                       const float* __restrict__ w_v, const float* __restrict__ b_v,
                       const float* __restrict__ w_o, const float* __restrict__ b_o,
                       unsigned short* __restrict__ WT, unsigned short* __restrict__ WeT,
                       unsigned short* __restrict__ WoT, float* __restrict__ bias384,
                       float* __restrict__ bkB, float* __restrict__ boB) {
  int t = blockIdx.x * 256 + threadIdx.x;
  if (t < 49152) {
    int n = t >> 7, k = t & 127;
    const float* wsel; int nn; float scale = 1.0f;
    if (n < 128)      { wsel = w_q; nn = n;       scale = 0.25f; }
    else if (n < 256) { wsel = w_k; nn = n - 128; }
    else              { wsel = w_v; nn = n - 256; }
    float s = 0.f;
    for (int d = 0; d < 128; ++d) s += w_lin[k*128 + d] * wsel[d*128 + nn];
    WT[n*128 + k] = f2bf(s * scale);
  } else if (t < 57344) {          // WeT: 128*64
    int i = t - 49152, n = i >> 6, k = i & 63;
    float s = 0.f;
    for (int d = 0; d < 128; ++d) s += w_e[k*128 + d] * w_k[d*128 + n];
    WeT[n*64 + k] = f2bf(s);
  } else if (t < 73728) {          // WoT: 128*128 transpose
    int i = t - 57344, n = i >> 7, k = i & 127;
    WoT[n*128 + k] = f2bf(w_o[k*128 + n]);
  } else if (t < 74112) {          // bias384 = [b_q/4, 0, b_v]
    int i = t - 73728;
    bias384[i] = (i < 128) ? b_q[i] * 0.25f : ((i < 256) ? 0.f : b_v[i - 256]);
  } else if (t < 74240) {
    bkB[t - 74112] = b_k[t - 74112];
  } else if (t < 74368) {
    boB[t - 74240] = b_o[t - 74240];
  }
}

// ---------------- K1: qkv = x @ WT^T + bias  (M=N, K=128, Ncols=384), bf16 out ----------------
__global__ __launch_bounds__(256) void k_qkv(const float* __restrict__ x,
                                             const unsigned short* __restrict__ WT,
                                             const float* __restrict__ bias,
                                             unsigned short* __restrict__ qkv) {
  __shared__ unsigned short As[64][136];
  __shared__ unsigned short Bs[64][136];
  int tid = threadIdx.x;
  int row0 = blockIdx.x * 64;
  #pragma unroll
  for (int it = 0; it < 8; ++it) {          // A: 64x128 f32 -> bf16, staged once
    int i4 = tid + it * 256;
    int r = i4 >> 5, c4 = i4 & 31;
    float4 vv = make_float4(0.f, 0.f, 0.f, 0.f);
    int gr = row0 + r;
    if (gr < NN) vv = *(const float4*)(x + (size_t)gr * 128 + c4 * 4);
    us4 s4 = { f2bf(vv.x), f2bf(vv.y), f2bf(vv.z), f2bf(vv.w) };
    *(us4*)(&As[r][c4 * 4]) = s4;
  }
  int w = tid >> 6, lane = tid & 63, lr = lane & 15, lk = lane >> 4;
  for (int yb = 0; yb < 6; ++yb) {
    int col0 = yb * 64;
    __syncthreads();
    #pragma unroll
    for (int it = 0; it < 8; ++it) {
      int i4 = tid + it * 256;
      int r = i4 >> 5, c4 = i4 & 31;
      *(us4*)(&Bs[r][c4 * 4]) = *(const us4*)(WT + (size_t)(col0 + r) * 128 + c4 * 4);
    }
    __syncthreads();
    f32x4 acc[4] = {};
    #pragma unroll
    for (int kk = 0; kk < 4; ++kk) {
      int kof = kk * 32 + lk * 8;
      bf16x8 af = *(const bf16x8*)(&As[w * 16 + lr][kof]);
      #pragma unroll
      for (int nt = 0; nt < 4; ++nt) {
        bf16x8 bfrag = *(const bf16x8*)(&Bs[nt * 16 + lr][kof]);
        acc[nt] = __builtin_amdgcn_mfma_f32_16x16x32_bf16(af, bfrag, acc[nt], 0, 0, 0);
      }
    }
    #pragma unroll
    for (int nt = 0; nt < 4; ++nt) {
      int gcol = col0 + nt * 16 + lr;
      float b = bias[gcol];
      #pragma unroll
      for (int j = 0; j < 4; ++j) {
        int grow = row0 + w * 16 + lk * 4 + j;
        if (grow < NN) qkv[(size_t)grow * 384 + gcol] = f2bf(acc[nt][j] + b);
      }
    }
  }
}

// ---------------- K2: Ke = edge_attr @ WeT^T + b_k  (M=E, K=64, Ncols=128), bf16 out ----------------
__global__ __launch_bounds__(256) void k_ke(const float* __restrict__ ea,
                                            const unsigned short* __restrict__ WeT,
                                            const float* __restrict__ bk,
                                            unsigned short* __restrict__ ke) {
  __shared__ unsigned short As[64][72];
  __shared__ unsigned short Bs[64][72];
  int tid = threadIdx.x;
  int row0 = blockIdx.x * 64;
  int col0 = blockIdx.y * 64;
  #pragma unroll
  for (int it = 0; it < 4; ++it) {
    int i4 = tid + it * 256;
    int r = i4 >> 4, c4 = i4 & 15;
    float4 vv = make_float4(0.f, 0.f, 0.f, 0.f);
    int gr = row0 + r;
    if (gr < EE) vv = *(const float4*)(ea + (size_t)gr * 64 + c4 * 4);
    us4 s4 = { f2bf(vv.x), f2bf(vv.y), f2bf(vv.z), f2bf(vv.w) };
    *(us4*)(&As[r][c4 * 4]) = s4;
  }
  #pragma unroll
  for (int it = 0; it < 4; ++it) {
    int i4 = tid + it * 256;
    int r = i4 >> 4, c4 = i4 & 15;
    us4 s4 = *(const us4*)(WeT + (size_t)(col0 + r) * 64 + c4 * 4);
    *(us4*)(&Bs[r][c4 * 4]) = s4;
  }
  __syncthreads();
  int w = tid >> 6, lane = tid & 63, lr = lane & 15, lk = lane >> 4;
  f32x4 acc[4] = {};
  #pragma unroll
  for (int kk = 0; kk < 2; ++kk) {
    int kof = kk * 32 + lk * 8;
    bf16x8 af = *(const bf16x8*)(&As[w * 16 + lr][kof]);
    #pragma unroll
    for (int nt = 0; nt < 4; ++nt) {
      bf16x8 bfrag = *(const bf16x8*)(&Bs[nt * 16 + lr][kof]);
      acc[nt] = __builtin_amdgcn_mfma_f32_16x16x32_bf16(af, bfrag, acc[nt], 0, 0, 0);
    }
  }
  #pragma unroll
  for (int nt = 0; nt < 4; ++nt) {
    int gcol = col0 + nt * 16 + lr;
    float b = bk[gcol];
    #pragma unroll
    for (int j = 0; j < 4; ++j) {
      int grow = row0 + w * 16 + lk * 4 + j;
      if (grow < EE) ke[(size_t)grow * 128 + gcol] = f2bf(acc[nt][j] + b);
    }
  }
}

// ---------------- CSR build: count -> parallel scan -> scatter(pos) ----------------
__global__ void k_count(const int* __restrict__ owners, int* __restrict__ counts) {
  int g = blockIdx.x * 256 + threadIdx.x;
  if (g < GG) atomicAdd(counts + owners[(size_t)g * 4], 1);
}

__global__ __launch_bounds__(256) void k_scan1(const int* __restrict__ counts,
                                               int* __restrict__ lofs,
                                               int* __restrict__ bsums) {
  __shared__ int tmp[256];
  int tid = threadIdx.x;
  int i = blockIdx.x * 256 + tid;
  int v = (i < NN) ? counts[i] : 0;
  tmp[tid] = v;
  __syncthreads();
  int val = v;
  #pragma unroll
  for (int off = 1; off < 256; off <<= 1) {
    int t = (tid >= off) ? tmp[tid - off] : 0;
    __syncthreads();
    val += t;
    tmp[tid] = val;
    __syncthreads();
  }
  if (i < NN) lofs[i] = val - v;
  if (tid == 255) bsums[blockIdx.x] = val;
}

__global__ __launch_bounds__(512) void k_scan2(int* __restrict__ bsums) {
  __shared__ int tmp[512];
  int tid = threadIdx.x;
  int v = (tid < NB) ? bsums[tid] : 0;
  tmp[tid] = v;
  __syncthreads();
  int val = v;
  #pragma unroll
  for (int off = 1; off < 512; off <<= 1) {
    int t = (tid >= off) ? tmp[tid - off] : 0;
    __syncthreads();
    val += t;
    tmp[tid] = val;
    __syncthreads();
  }
  if (tid < NB) bsums[tid] = val - v;
}

__global__ void k_scan3(const int* __restrict__ lofs, const int* __restrict__ bsums,
                        int* __restrict__ starts, int* __restrict__ wcursor) {
  int i = blockIdx.x * 256 + threadIdx.x;
  if (i < NN) {
    int s = lofs[i] + bsums[i >> 8];
    starts[i] = s;
    wcursor[i] = s;
  }
  if (i == 0) starts[NN] = GG;
}

__global__ void k_scatter(const int* __restrict__ owners, int* __restrict__ wcursor,
                          int* __restrict__ pos) {
  int g = blockIdx.x * 256 + threadIdx.x;
  if (g < GG) {
    int v = owners[(size_t)g * 4];
    pos[g] = atomicAdd(wcursor + v, 1);      // CSR slot for this group
  }
}

// ---------------- K3: per-EDGE pass — 16 scores, 4 owner partials, slot writes ----------------
// One wave per edge. Members m0..m3 (= pair_u[16e..16e+3]); owner of group 4e+i is m_i.
// Gathers 4 full qkv rows (q,k,v all used) + 1 Ke row; writes 4 unnormalized
// partial ctx rows (bf16) + per-head denoms (f32) to CSR slots. No atomics.
__global__ __launch_bounds__(256) void k_edge(const unsigned short* __restrict__ qkv,
                                              const unsigned short* __restrict__ ke,
                                              const int* __restrict__ pair_u,
                                              const int* __restrict__ pos,
                                              unsigned short* __restrict__ pctx,
                                              float* __restrict__ pden) {
  int e = blockIdx.x * 4 + (threadIdx.x >> 6);
  if (e >= EE) return;
  int lane = threadIdx.x & 63;
  int m[4], ps[4];
  #pragma unroll
  for (int j = 0; j < 4; ++j) {
    m[j]  = __builtin_amdgcn_readfirstlane(pair_u[(size_t)e * 16 + j]);
    ps[j] = __builtin_amdgcn_readfirstlane(pos[(size_t)e * 4 + j]);
  }
  unsigned int kew = *(const unsigned int*)(ke + (size_t)e * 128 + 2 * lane);
  float e0 = bf2f(kew & 0xffffu), e1 = bf2f(kew >> 16);
  float qa[4][2], ka[4][2], va[4][2];
  #pragma unroll
  for (int j = 0; j < 4; ++j) {
    const unsigned short* r = qkv + (size_t)m[j] * 384 + 2 * lane;
    unsigned int qw = *(const unsigned int*)r;
    unsigned int kw = *(const unsigned int*)(r + 128);
    unsigned int vw = *(const unsigned int*)(r + 256);
    qa[j][0] = bf2f(qw & 0xffffu);      qa[j][1] = bf2f(qw >> 16);
    ka[j][0] = bf2f(kw & 0xffffu) + e0; ka[j][1] = bf2f(kw >> 16) + e1;
    va[j][0] = bf2f(vw & 0xffffu);      va[j][1] = bf2f(vw >> 16);
  }
  #pragma unroll
  for (int i = 0; i < 4; ++i) {
    float c0 = 0.f, c1 = 0.f, ds = 0.f;
    #pragma unroll
    for (int j = 0; j < 4; ++j) {
      float sc = qa[i][0] * ka[j][0] + qa[i][1] * ka[j][1];
      sc += __shfl_xor(sc, 1);
      sc += __shfl_xor(sc, 2);
      sc += __shfl_xor(sc, 4);                 // head-local sum (8 lanes/head)
      float ex = __expf(sc);                   // |scores| small: no max-sub pass
      c0 += ex * va[j][0];
      c1 += ex * va[j][1];
      ds += ex;
    }
    unsigned int packed = (unsigned int)f2bf(c0) | ((unsigned int)f2bf(c1) << 16);
    *(unsigned int*)(pctx + (size_t)ps[i] * 128 + 2 * lane) = packed;
    if ((lane & 7) == 0) pden[(size_t)ps[i] * 8 + (lane >> 3)] = ds;
  }
}

// ---------------- K4: out = relu( (sum slots / denom) @ WoT^T + b_o ), f32 out ----------------
// A-stage sums each row's contiguous CSR slot range and normalizes (fuses k_nodesum).
__global__ __launch_bounds__(256) void k_out(const unsigned short* __restrict__ pctx,
                                             const float* __restrict__ pden,
                                             const int* __restrict__ starts,
                                             const unsigned short* __restrict__ WoT,
                                             const float* __restrict__ bo,
                                             float* __restrict__ out) {
  __shared__ unsigned short As[64][136];
  __shared__ unsigned short Bs[128][136];
  int tid = threadIdx.x;
  int row0 = blockIdx.x * 64;
  #pragma unroll
  for (int it = 0; it < 8; ++it) {
    int i4 = tid + it * 256;
    int r = i4 >> 5, c4 = i4 & 31;
    int gr = row0 + r;
    float a0 = 0.f, a1 = 0.f, a2 = 0.f, a3 = 0.f, ds = 0.f;
    if (gr < NN) {
      int s0 = starts[gr], s1 = starts[gr + 1];
      for (int sl = s0; sl < s1; ++sl) {
        us4 wv = *(const us4*)(pctx + (size_t)sl * 128 + c4 * 4);
        a0 += bf2f(wv.x); a1 += bf2f(wv.y); a2 += bf2f(wv.z); a3 += bf2f(wv.w);
        ds += pden[(size_t)sl * 8 + (c4 >> 2)];
      }
    }
    float inv = ds > 0.f ? 1.0f / ds : 0.f;
    us4 s4 = { f2bf(a0 * inv), f2bf(a1 * inv), f2bf(a2 * inv), f2bf(a3 * inv) };
    *(us4*)(&As[r][c4 * 4]) = s4;
  }
  #pragma unroll
  for (int it = 0; it < 16; ++it) {
    int i4 = tid + it * 256;
    int r = i4 >> 5, c4 = i4 & 31;
    *(us4*)(&Bs[r][c4 * 4]) = *(const us4*)(WoT + (size_t)r * 128 + c4 * 4);
  }
  __syncthreads();
  int w = tid >> 6, lane = tid & 63, lr = lane & 15, lk = lane >> 4;
  f32x4 acc[8] = {};
  #pragma unroll
  for (int kk = 0; kk < 4; ++kk) {
    int kof = kk * 32 + lk * 8;
    bf16x8 af = *(const bf16x8*)(&As[w * 16 + lr][kof]);
    #pragma unroll
    for (int nt = 0; nt < 8; ++nt) {
      bf16x8 bfrag = *(const bf16x8*)(&Bs[nt * 16 + lr][kof]);
      acc[nt] = __builtin_amdgcn_mfma_f32_16x16x32_bf16(af, bfrag, acc[nt], 0, 0, 0);
    }
  }
  #pragma unroll
  for (int nt = 0; nt < 8; ++nt) {
    int gcol = nt * 16 + lr;
    float b = bo[gcol];
    #pragma unroll
    for (int j = 0; j < 4; ++j) {
      int grow = row0 + w * 16 + lk * 4 + j;
      if (grow < NN) {
        float vvv = acc[nt][j] + b;
        out[(size_t)grow * 128 + gcol] = vvv > 0.f ? vvv : 0.f;
      }
    }
  }
}

extern "C" void kernel_launch(void* const* d_in, const int* in_sizes, int n_in,
                              void* d_out, int out_size, void* d_ws, size_t ws_size,
                              hipStream_t stream) {
  const float* x      = (const float*)d_in[0];
  const float* ea     = (const float*)d_in[1];
  const float* w_lin  = (const float*)d_in[2];
  const float* w_e    = (const float*)d_in[3];
  const float* w_q    = (const float*)d_in[4];
  const float* b_q    = (const float*)d_in[5];
  const float* w_k    = (const float*)d_in[6];
  const float* b_k    = (const float*)d_in[7];
  const float* w_v    = (const float*)d_in[8];
  const float* b_v    = (const float*)d_in[9];
  const float* w_o    = (const float*)d_in[10];
  const float* b_o    = (const float*)d_in[11];
  const int* owners   = (const int*)d_in[12];
  const int* pair_u   = (const int*)d_in[14];
  float* out = (float*)d_out;

  char* base = (char*)d_ws;
  size_t o = 0;
  auto alloc = [&](size_t b) {
    void* p = base + o;
    o = (o + b + 255) & ~(size_t)255;
    return p;
  };
  unsigned short* WT      = (unsigned short*)alloc((size_t)384 * 128 * 2);
  unsigned short* WeT     = (unsigned short*)alloc((size_t)128 * 64 * 2);
  unsigned short* WoT     = (unsigned short*)alloc((size_t)128 * 128 * 2);
  float* bias384          = (float*)alloc(384 * 4);
  float* bkB              = (float*)alloc(128 * 4);
  float* boB              = (float*)alloc(128 * 4);
  unsigned short* qkv     = (unsigned short*)alloc((size_t)NN * 384 * 2);
  unsigned short* keb     = (unsigned short*)alloc((size_t)EE * 128 * 2);
  int* counts             = (int*)alloc((size_t)NN * 4);
  int* starts             = (int*)alloc((size_t)(NN + 1) * 4);
  int* wcursor            = (int*)alloc((size_t)NN * 4);
  int* pos                = (int*)alloc((size_t)GG * 4);
  int* lofs               = (int*)alloc((size_t)NN * 4);
  int* bsums              = (int*)alloc((size_t)NB * 4);
  unsigned short* pctx    = (unsigned short*)alloc((size_t)GG * 128 * 2);
  float* pden             = (float*)alloc((size_t)GG * 8 * 4);

  hipMemsetAsync(counts, 0, (size_t)NN * 4, stream);

  k_prep<<<291, 256, 0, stream>>>(w_lin, w_e, w_q, b_q, w_k, b_k, w_v, b_v, w_o, b_o,
                                  WT, WeT, WoT, bias384, bkB, boB);
  k_qkv<<<1563, 256, 0, stream>>>(x, WT, bias384, qkv);
  k_ke<<<dim3(782, 2), 256, 0, stream>>>(ea, WeT, bkB, keb);
  k_count<<<782, 256, 0, stream>>>(owners, counts);
  k_scan1<<<NB, 256, 0, stream>>>(counts, lofs, bsums);
  k_scan2<<<1, 512, 0, stream>>>(bsums);
  k_scan3<<<NB, 256, 0, stream>>>(lofs, bsums, starts, wcursor);
  k_scatter<<<782, 256, 0, stream>>>(owners, wcursor, pos);
  k_edge<<<12500, 256, 0, stream>>>(qkv, keb, pair_u, pos, pctx, pden);
  k_out<<<1563, 256, 0, stream>>>(pctx, pden, starts, WoT, boB, out);
}

// Round 5
// 190.615 us; speedup vs baseline: 2.3262x; 1.0131x over previous
//
#include <hip/hip_runtime.h>

#define NN 100000
#define EE 50000
#define GG (EE*4)   // owner groups (4 pairs each, same owner, same edge)
#define NB 391      // ceil(NN/256)

typedef __attribute__((ext_vector_type(8))) short bf16x8;
typedef __attribute__((ext_vector_type(4))) float f32x4;

__device__ __forceinline__ unsigned short f2bf(float f) {
  union { float f; unsigned int u; } c; c.f = f;
  unsigned int u = c.u;
  u = (u + 0x7fffu + ((u >> 16) & 1u)) >> 16;
  return (unsigned short)u;
}
__device__ __forceinline__ float bf2f(unsigned int lo16) {
  union { unsigned int u; float f; } c; c.u = lo16 << 16;
  return c.f;
}

struct __align__(8) us4 { unsigned short x, y, z, w; };

// ---------------- K0: combine weights on device (tiny) ----------------
__global__ void k_prep(const float* __restrict__ w_lin, const float* __restrict__ w_e,
                       const float* __restrict__ w_q, const float* __restrict__ b_q,
                       const float* __restrict__ w_k, const float* __restrict__ b_k,
                       const float* __restrict__ w_v, const float* __restrict__ b_v,
                       const float* __restrict__ w_o, const float* __restrict__ b_o,
                       unsigned short* __restrict__ WT, unsigned short* __restrict__ WeT,
                       unsigned short* __restrict__ WoT, float* __restrict__ bias384,
                       float* __restrict__ bkB, float* __restrict__ boB) {
  int t = blockIdx.x * 256 + threadIdx.x;
  if (t < 49152) {
    int n = t >> 7, k = t & 127;
    const float* wsel; int nn; float scale = 1.0f;
    if (n < 128)      { wsel = w_q; nn = n;       scale = 0.25f; }
    else if (n < 256) { wsel = w_k; nn = n - 128; }
    else              { wsel = w_v; nn = n - 256; }
    float s = 0.f;
    for (int d = 0; d < 128; ++d) s += w_lin[k*128 + d] * wsel[d*128 + nn];
    WT[n*128 + k] = f2bf(s * scale);
  } else if (t < 57344) {          // WeT: 128*64
    int i = t - 49152, n = i >> 6, k = i & 63;
    float s = 0.f;
    for (int d = 0; d < 128; ++d) s += w_e[k*128 + d] * w_k[d*128 + n];
    WeT[n*64 + k] = f2bf(s);
  } else if (t < 73728) {          // WoT: 128*128 transpose
    int i = t - 57344, n = i >> 7, k = i & 127;
    WoT[n*128 + k] = f2bf(w_o[k*128 + n]);
  } else if (t < 74112) {          // bias384 = [b_q/4, 0, b_v]
    int i = t - 73728;
    bias384[i] = (i < 128) ? b_q[i] * 0.25f : ((i < 256) ? 0.f : b_v[i - 256]);
  } else if (t < 74240) {
    bkB[t - 74112] = b_k[t - 74112];
  } else if (t < 74368) {
    boB[t - 74240] = b_o[t - 74240];
  }
}

// ---------------- K1: qkv = x @ WT^T + bias  (M=N, K=128, Ncols=384), bf16 out ----------------
// v2: A staged once in XOR-swizzled LDS (1 barrier); B fragments straight from
// L2-resident WT; each wave owns 64 rows x 96 cols; A frags held in registers.
__global__ __launch_bounds__(256) void k_qkv(const float* __restrict__ x,
                                             const unsigned short* __restrict__ WT,
                                             const float* __restrict__ bias,
                                             unsigned short* __restrict__ qkv) {
  // As[64 rows][128 shorts], row stride 256B, 16B chunks swizzled: chunk ^= (row&7)
  __shared__ unsigned short As[64 * 128];
  int tid = threadIdx.x;
  int row0 = blockIdx.x * 64;
  #pragma unroll
  for (int it = 0; it < 8; ++it) {          // A: 64x128 f32 -> bf16, swizzled store
    int i4 = tid + it * 256;
    int r = i4 >> 5, c4 = i4 & 31;          // c4: 4-short (8B) index within row
    float4 vv = make_float4(0.f, 0.f, 0.f, 0.f);
    int gr = row0 + r;
    if (gr < NN) vv = *(const float4*)(x + (size_t)gr * 128 + c4 * 4);
    us4 s4 = { f2bf(vv.x), f2bf(vv.y), f2bf(vv.z), f2bf(vv.w) };
    int chunk = c4 >> 1;
    int soff = r * 128 + ((chunk ^ (r & 7)) << 3) + ((c4 & 1) << 2);
    *(us4*)(&As[soff]) = s4;
  }
  __syncthreads();
  int w = tid >> 6, lane = tid & 63, lr = lane & 15, lk = lane >> 4;
  // A fragments: rows rt*16+lr, k-chunk kk*32+lk*8 -> swizzled chunk (kk*4+lk)^(row&7)
  bf16x8 afr[4][4];
  #pragma unroll
  for (int rt = 0; rt < 4; ++rt) {
    int R = rt * 16 + lr;
    #pragma unroll
    for (int kk = 0; kk < 4; ++kk) {
      int chunk = (kk * 4 + lk) ^ (R & 7);
      afr[rt][kk] = *(const bf16x8*)(&As[R * 128 + chunk * 8]);
    }
  }
  #pragma unroll
  for (int ct = 0; ct < 6; ++ct) {
    int gcol = w * 96 + ct * 16 + lr;
    const unsigned short* bp = WT + (size_t)gcol * 128 + lk * 8;
    bf16x8 bfr0 = *(const bf16x8*)(bp);
    bf16x8 bfr1 = *(const bf16x8*)(bp + 32);
    bf16x8 bfr2 = *(const bf16x8*)(bp + 64);
    bf16x8 bfr3 = *(const bf16x8*)(bp + 96);
    f32x4 acc[4] = {};
    #pragma unroll
    for (int rt = 0; rt < 4; ++rt) {
      acc[rt] = __builtin_amdgcn_mfma_f32_16x16x32_bf16(afr[rt][0], bfr0, acc[rt], 0, 0, 0);
      acc[rt] = __builtin_amdgcn_mfma_f32_16x16x32_bf16(afr[rt][1], bfr1, acc[rt], 0, 0, 0);
      acc[rt] = __builtin_amdgcn_mfma_f32_16x16x32_bf16(afr[rt][2], bfr2, acc[rt], 0, 0, 0);
      acc[rt] = __builtin_amdgcn_mfma_f32_16x16x32_bf16(afr[rt][3], bfr3, acc[rt], 0, 0, 0);
    }
    float b = bias[gcol];
    #pragma unroll
    for (int rt = 0; rt < 4; ++rt) {
      #pragma unroll
      for (int j = 0; j < 4; ++j) {
        int grow = row0 + rt * 16 + lk * 4 + j;
        if (grow < NN) qkv[(size_t)grow * 384 + gcol] = f2bf(acc[rt][j] + b);
      }
    }
  }
}

// ---------------- K2: Ke = edge_attr @ WeT^T + b_k  (M=E, K=64, Ncols=128), bf16 out ----------------
__global__ __launch_bounds__(256) void k_ke(const float* __restrict__ ea,
                                            const unsigned short* __restrict__ WeT,
                                            const float* __restrict__ bk,
                                            unsigned short* __restrict__ ke) {
  __shared__ unsigned short As[64][72];
  __shared__ unsigned short Bs[64][72];
  int tid = threadIdx.x;
  int row0 = blockIdx.x * 64;
  int col0 = blockIdx.y * 64;
  #pragma unroll
  for (int it = 0; it < 4; ++it) {
    int i4 = tid + it * 256;
    int r = i4 >> 4, c4 = i4 & 15;
    float4 vv = make_float4(0.f, 0.f, 0.f, 0.f);
    int gr = row0 + r;
    if (gr < EE) vv = *(const float4*)(ea + (size_t)gr * 64 + c4 * 4);
    us4 s4 = { f2bf(vv.x), f2bf(vv.y), f2bf(vv.z), f2bf(vv.w) };
    *(us4*)(&As[r][c4 * 4]) = s4;
  }
  #pragma unroll
  for (int it = 0; it < 4; ++it) {
    int i4 = tid + it * 256;
    int r = i4 >> 4, c4 = i4 & 15;
    us4 s4 = *(const us4*)(WeT + (size_t)(col0 + r) * 64 + c4 * 4);
    *(us4*)(&Bs[r][c4 * 4]) = s4;
  }
  __syncthreads();
  int w = tid >> 6, lane = tid & 63, lr = lane & 15, lk = lane >> 4;
  f32x4 acc[4] = {};
  #pragma unroll
  for (int kk = 0; kk < 2; ++kk) {
    int kof = kk * 32 + lk * 8;
    bf16x8 af = *(const bf16x8*)(&As[w * 16 + lr][kof]);
    #pragma unroll
    for (int nt = 0; nt < 4; ++nt) {
      bf16x8 bfrag = *(const bf16x8*)(&Bs[nt * 16 + lr][kof]);
      acc[nt] = __builtin_amdgcn_mfma_f32_16x16x32_bf16(af, bfrag, acc[nt], 0, 0, 0);
    }
  }
  #pragma unroll
  for (int nt = 0; nt < 4; ++nt) {
    int gcol = col0 + nt * 16 + lr;
    float b = bk[gcol];
    #pragma unroll
    for (int j = 0; j < 4; ++j) {
      int grow = row0 + w * 16 + lk * 4 + j;
      if (grow < EE) ke[(size_t)grow * 128 + gcol] = f2bf(acc[nt][j] + b);
    }
  }
}

// ---------------- CSR build: count -> parallel scan -> scatter(pos) ----------------
__global__ void k_count(const int* __restrict__ owners, int* __restrict__ counts) {
  int g = blockIdx.x * 256 + threadIdx.x;
  if (g < GG) atomicAdd(counts + owners[(size_t)g * 4], 1);
}

__global__ __launch_bounds__(256) void k_scan1(const int* __restrict__ counts,
                                               int* __restrict__ lofs,
                                               int* __restrict__ bsums) {
  __shared__ int tmp[256];
  int tid = threadIdx.x;
  int i = blockIdx.x * 256 + tid;
  int v = (i < NN) ? counts[i] : 0;
  tmp[tid] = v;
  __syncthreads();
  int val = v;
  #pragma unroll
  for (int off = 1; off < 256; off <<= 1) {
    int t = (tid >= off) ? tmp[tid - off] : 0;
    __syncthreads();
    val += t;
    tmp[tid] = val;
    __syncthreads();
  }
  if (i < NN) lofs[i] = val - v;
  if (tid == 255) bsums[blockIdx.x] = val;
}

__global__ __launch_bounds__(512) void k_scan2(int* __restrict__ bsums) {
  __shared__ int tmp[512];
  int tid = threadIdx.x;
  int v = (tid < NB) ? bsums[tid] : 0;
  tmp[tid] = v;
  __syncthreads();
  int val = v;
  #pragma unroll
  for (int off = 1; off < 512; off <<= 1) {
    int t = (tid >= off) ? tmp[tid - off] : 0;
    __syncthreads();
    val += t;
    tmp[tid] = val;
    __syncthreads();
  }
  if (tid < NB) bsums[tid] = val - v;
}

__global__ void k_scan3(const int* __restrict__ lofs, const int* __restrict__ bsums,
                        int* __restrict__ starts, int* __restrict__ wcursor) {
  int i = blockIdx.x * 256 + threadIdx.x;
  if (i < NN) {
    int s = lofs[i] + bsums[i >> 8];
    starts[i] = s;
    wcursor[i] = s;
  }
  if (i == 0) starts[NN] = GG;
}

__global__ void k_scatter(const int* __restrict__ owners, int* __restrict__ wcursor,
                          int* __restrict__ pos) {
  int g = blockIdx.x * 256 + threadIdx.x;
  if (g < GG) {
    int v = owners[(size_t)g * 4];
    pos[g] = atomicAdd(wcursor + v, 1);      // CSR slot for this group
  }
}

// ---------------- K3: per-EDGE pass — 16 scores, 4 owner partials, slot writes ----------------
__global__ __launch_bounds__(256) void k_edge(const unsigned short* __restrict__ qkv,
                                              const unsigned short* __restrict__ ke,
                                              const int* __restrict__ pair_u,
                                              const int* __restrict__ pos,
                                              unsigned short* __restrict__ pctx,
                                              float* __restrict__ pden) {
  int e = blockIdx.x * 4 + (threadIdx.x >> 6);
  if (e >= EE) return;
  int lane = threadIdx.x & 63;
  int m[4], ps[4];
  #pragma unroll
  for (int j = 0; j < 4; ++j) {
    m[j]  = __builtin_amdgcn_readfirstlane(pair_u[(size_t)e * 16 + j]);
    ps[j] = __builtin_amdgcn_readfirstlane(pos[(size_t)e * 4 + j]);
  }
  unsigned int kew = *(const unsigned int*)(ke + (size_t)e * 128 + 2 * lane);
  float e0 = bf2f(kew & 0xffffu), e1 = bf2f(kew >> 16);
  float qa[4][2], ka[4][2], va[4][2];
  #pragma unroll
  for (int j = 0; j < 4; ++j) {
    const unsigned short* r = qkv + (size_t)m[j] * 384 + 2 * lane;
    unsigned int qw = *(const unsigned int*)r;
    unsigned int kw = *(const unsigned int*)(r + 128);
    unsigned int vw = *(const unsigned int*)(r + 256);
    qa[j][0] = bf2f(qw & 0xffffu);      qa[j][1] = bf2f(qw >> 16);
    ka[j][0] = bf2f(kw & 0xffffu) + e0; ka[j][1] = bf2f(kw >> 16) + e1;
    va[j][0] = bf2f(vw & 0xffffu);      va[j][1] = bf2f(vw >> 16);
  }
  #pragma unroll
  for (int i = 0; i < 4; ++i) {
    float c0 = 0.f, c1 = 0.f, ds = 0.f;
    #pragma unroll
    for (int j = 0; j < 4; ++j) {
      float sc = qa[i][0] * ka[j][0] + qa[i][1] * ka[j][1];
      sc += __shfl_xor(sc, 1);
      sc += __shfl_xor(sc, 2);
      sc += __shfl_xor(sc, 4);                 // head-local sum (8 lanes/head)
      float ex = __expf(sc);                   // |scores| small: no max-sub pass
      c0 += ex * va[j][0];
      c1 += ex * va[j][1];
      ds += ex;
    }
    unsigned int packed = (unsigned int)f2bf(c0) | ((unsigned int)f2bf(c1) << 16);
    *(unsigned int*)(pctx + (size_t)ps[i] * 128 + 2 * lane) = packed;
    if ((lane & 7) == 0) pden[(size_t)ps[i] * 8 + (lane >> 3)] = ds;
  }
}

// ---------------- K4: out = relu( (sum slots / denom) @ WoT^T + b_o ), f32 out ----------------
__global__ __launch_bounds__(256) void k_out(const unsigned short* __restrict__ pctx,
                                             const float* __restrict__ pden,
                                             const int* __restrict__ starts,
                                             const unsigned short* __restrict__ WoT,
                                             const float* __restrict__ bo,
                                             float* __restrict__ out) {
  __shared__ unsigned short As[64][136];
  __shared__ unsigned short Bs[128][136];
  int tid = threadIdx.x;
  int row0 = blockIdx.x * 64;
  #pragma unroll
  for (int it = 0; it < 8; ++it) {
    int i4 = tid + it * 256;
    int r = i4 >> 5, c4 = i4 & 31;
    int gr = row0 + r;
    float a0 = 0.f, a1 = 0.f, a2 = 0.f, a3 = 0.f, ds = 0.f;
    if (gr < NN) {
      int s0 = starts[gr], s1 = starts[gr + 1];
      for (int sl = s0; sl < s1; ++sl) {
        us4 wv = *(const us4*)(pctx + (size_t)sl * 128 + c4 * 4);
        a0 += bf2f(wv.x); a1 += bf2f(wv.y); a2 += bf2f(wv.z); a3 += bf2f(wv.w);
        ds += pden[(size_t)sl * 8 + (c4 >> 2)];
      }
    }
    float inv = ds > 0.f ? 1.0f / ds : 0.f;
    us4 s4 = { f2bf(a0 * inv), f2bf(a1 * inv), f2bf(a2 * inv), f2bf(a3 * inv) };
    *(us4*)(&As[r][c4 * 4]) = s4;
  }
  #pragma unroll
  for (int it = 0; it < 16; ++it) {
    int i4 = tid + it * 256;
    int r = i4 >> 5, c4 = i4 & 31;
    *(us4*)(&Bs[r][c4 * 4]) = *(const us4*)(WoT + (size_t)r * 128 + c4 * 4);
  }
  __syncthreads();
  int w = tid >> 6, lane = tid & 63, lr = lane & 15, lk = lane >> 4;
  f32x4 acc[8] = {};
  #pragma unroll
  for (int kk = 0; kk < 4; ++kk) {
    int kof = kk * 32 + lk * 8;
    bf16x8 af = *(const bf16x8*)(&As[w * 16 + lr][kof]);
    #pragma unroll
    for (int nt = 0; nt < 8; ++nt) {
      bf16x8 bfrag = *(const bf16x8*)(&Bs[nt * 16 + lr][kof]);
      acc[nt] = __builtin_amdgcn_mfma_f32_16x16x32_bf16(af, bfrag, acc[nt], 0, 0, 0);
    }
  }
  #pragma unroll
  for (int nt = 0; nt < 8; ++nt) {
    int gcol = nt * 16 + lr;
    float b = bo[gcol];
    #pragma unroll
    for (int j = 0; j < 4; ++j) {
      int grow = row0 + w * 16 + lk * 4 + j;
      if (grow < NN) {
        float vvv = acc[nt][j] + b;
        out[(size_t)grow * 128 + gcol] = vvv > 0.f ? vvv : 0.f;
      }
    }
  }
}

extern "C" void kernel_launch(void* const* d_in, const int* in_sizes, int n_in,
                              void* d_out, int out_size, void* d_ws, size_t ws_size,
                              hipStream_t stream) {
  const float* x      = (const float*)d_in[0];
  const float* ea     = (const float*)d_in[1];
  const float* w_lin  = (const float*)d_in[2];
  const float* w_e    = (const float*)d_in[3];
  const float* w_q    = (const float*)d_in[4];
  const float* b_q    = (const float*)d_in[5];
  const float* w_k    = (const float*)d_in[6];
  const float* b_k    = (const float*)d_in[7];
  const float* w_v    = (const float*)d_in[8];
  const float* b_v    = (const float*)d_in[9];
  const float* w_o    = (const float*)d_in[10];
  const float* b_o    = (const float*)d_in[11];
  const int* owners   = (const int*)d_in[12];
  const int* pair_u   = (const int*)d_in[14];
  float* out = (float*)d_out;

  char* base = (char*)d_ws;
  size_t o = 0;
  auto alloc = [&](size_t b) {
    void* p = base + o;
    o = (o + b + 255) & ~(size_t)255;
    return p;
  };
  unsigned short* WT      = (unsigned short*)alloc((size_t)384 * 128 * 2);
  unsigned short* WeT     = (unsigned short*)alloc((size_t)128 * 64 * 2);
  unsigned short* WoT     = (unsigned short*)alloc((size_t)128 * 128 * 2);
  float* bias384          = (float*)alloc(384 * 4);
  float* bkB              = (float*)alloc(128 * 4);
  float* boB              = (float*)alloc(128 * 4);
  unsigned short* qkv     = (unsigned short*)alloc((size_t)NN * 384 * 2);
  unsigned short* keb     = (unsigned short*)alloc((size_t)EE * 128 * 2);
  int* counts             = (int*)alloc((size_t)NN * 4);
  int* starts             = (int*)alloc((size_t)(NN + 1) * 4);
  int* wcursor            = (int*)alloc((size_t)NN * 4);
  int* pos                = (int*)alloc((size_t)GG * 4);
  int* lofs               = (int*)alloc((size_t)NN * 4);
  int* bsums              = (int*)alloc((size_t)NB * 4);
  unsigned short* pctx    = (unsigned short*)alloc((size_t)GG * 128 * 2);
  float* pden             = (float*)alloc((size_t)GG * 8 * 4);

  hipMemsetAsync(counts, 0, (size_t)NN * 4, stream);

  k_prep<<<291, 256, 0, stream>>>(w_lin, w_e, w_q, b_q, w_k, b_k, w_v, b_v, w_o, b_o,
                                  WT, WeT, WoT, bias384, bkB, boB);
  k_qkv<<<1563, 256, 0, stream>>>(x, WT, bias384, qkv);
  k_ke<<<dim3(782, 2), 256, 0, stream>>>(ea, WeT, bkB, keb);
  k_count<<<782, 256, 0, stream>>>(owners, counts);
  k_scan1<<<NB, 256, 0, stream>>>(counts, lofs, bsums);
  k_scan2<<<1, 512, 0, stream>>>(bsums);
  k_scan3<<<NB, 256, 0, stream>>>(lofs, bsums, starts, wcursor);
  k_scatter<<<782, 256, 0, stream>>>(owners, wcursor, pos);
  k_edge<<<12500, 256, 0, stream>>>(qkv, keb, pair_u, pos, pctx, pden);
  k_out<<<1563, 256, 0, stream>>>(pctx, pden, starts, WoT, boB, out);
}

// Round 6
// 180.656 us; speedup vs baseline: 2.4545x; 1.0551x over previous
//
#include <hip/hip_runtime.h>

#define NN 100000
#define EE 50000
#define GG (EE*4)   // owner groups (4 pairs each, same owner, same edge)
#define NB 391      // ceil(NN/256)

typedef __attribute__((ext_vector_type(8))) short bf16x8;
typedef __attribute__((ext_vector_type(4))) float f32x4;

__device__ __forceinline__ unsigned short f2bf(float f) {
  union { float f; unsigned int u; } c; c.f = f;
  unsigned int u = c.u;
  u = (u + 0x7fffu + ((u >> 16) & 1u)) >> 16;
  return (unsigned short)u;
}
__device__ __forceinline__ float bf2f(unsigned int lo16) {
  union { unsigned int u; float f; } c; c.u = lo16 << 16;
  return c.f;
}

struct __align__(8) us4 { unsigned short x, y, z, w; };

// ---------------- K0: combine weights on device (tiny) ----------------
__global__ void k_prep(const float* __restrict__ w_lin, const float* __restrict__ w_e,
                       const float* __restrict__ w_q, const float* __restrict__ b_q,
                       const float* __restrict__ w_k, const float* __restrict__ b_k,
                       const float* __restrict__ w_v, const float* __restrict__ b_v,
                       const float* __restrict__ w_o, const float* __restrict__ b_o,
                       unsigned short* __restrict__ WT, unsigned short* __restrict__ WeT,
                       unsigned short* __restrict__ WoT, float* __restrict__ bias384,
                       float* __restrict__ bkB, float* __restrict__ boB) {
  int t = blockIdx.x * 256 + threadIdx.x;
  if (t < 49152) {
    int n = t >> 7, k = t & 127;
    const float* wsel; int nn; float scale = 1.0f;
    if (n < 128)      { wsel = w_q; nn = n;       scale = 0.25f; }
    else if (n < 256) { wsel = w_k; nn = n - 128; }
    else              { wsel = w_v; nn = n - 256; }
    float s = 0.f;
    for (int d = 0; d < 128; ++d) s += w_lin[k*128 + d] * wsel[d*128 + nn];
    WT[n*128 + k] = f2bf(s * scale);
  } else if (t < 57344) {          // WeT: 128*64
    int i = t - 49152, n = i >> 6, k = i & 63;
    float s = 0.f;
    for (int d = 0; d < 128; ++d) s += w_e[k*128 + d] * w_k[d*128 + n];
    WeT[n*64 + k] = f2bf(s);
  } else if (t < 73728) {          // WoT: 128*128 transpose
    int i = t - 57344, n = i >> 7, k = i & 127;
    WoT[n*128 + k] = f2bf(w_o[k*128 + n]);
  } else if (t < 74112) {          // bias384 = [b_q/4, 0, b_v]
    int i = t - 73728;
    bias384[i] = (i < 128) ? b_q[i] * 0.25f : ((i < 256) ? 0.f : b_v[i - 256]);
  } else if (t < 74240) {
    bkB[t - 74112] = b_k[t - 74112];
  } else if (t < 74368) {
    boB[t - 74240] = b_o[t - 74240];
  }
}

// ---------------- K1: qkv = x @ WT^T + bias  (M=N, K=128, Ncols=384), bf16 out ----------------
// v3: A staged once in XOR-swizzled LDS; B straight from L2-resident WT;
// 3 epilogue passes through a padded LDS tile -> fully coalesced 16B stores.
__global__ __launch_bounds__(256) void k_qkv(const float* __restrict__ x,
                                             const unsigned short* __restrict__ WT,
                                             const float* __restrict__ bias,
                                             unsigned short* __restrict__ qkv) {
  // dual-use LDS: stage-A (stride 128 shorts, 16B-chunk swizzle) then
  // epilogue tile (stride 136 shorts, padded -> conflict-floor reads)
  __shared__ unsigned short As[64 * 136];
  int tid = threadIdx.x;
  int row0 = blockIdx.x * 64;
  #pragma unroll
  for (int it = 0; it < 8; ++it) {          // A: 64x128 f32 -> bf16, swizzled store
    int i4 = tid + it * 256;
    int r = i4 >> 5, c4 = i4 & 31;
    float4 vv = make_float4(0.f, 0.f, 0.f, 0.f);
    int gr = row0 + r;
    if (gr < NN) vv = *(const float4*)(x + (size_t)gr * 128 + c4 * 4);
    us4 s4 = { f2bf(vv.x), f2bf(vv.y), f2bf(vv.z), f2bf(vv.w) };
    int chunk = c4 >> 1;
    int soff = r * 128 + ((chunk ^ (r & 7)) << 3) + ((c4 & 1) << 2);
    *(us4*)(&As[soff]) = s4;
  }
  __syncthreads();
  int w = tid >> 6, lane = tid & 63, lr = lane & 15, lk = lane >> 4;
  bf16x8 afr[4][4];
  #pragma unroll
  for (int rt = 0; rt < 4; ++rt) {
    int R = rt * 16 + lr;
    #pragma unroll
    for (int kk = 0; kk < 4; ++kk) {
      int chunk = (kk * 4 + lk) ^ (R & 7);
      afr[rt][kk] = *(const bf16x8*)(&As[R * 128 + chunk * 8]);
    }
  }
  #pragma unroll
  for (int p = 0; p < 3; ++p) {
    f32x4 acc[2][4] = {};
    #pragma unroll
    for (int h = 0; h < 2; ++h) {
      int gcol = p * 128 + h * 64 + w * 16 + lr;
      const unsigned short* bp = WT + (size_t)gcol * 128 + lk * 8;
      bf16x8 b0 = *(const bf16x8*)(bp);
      bf16x8 b1 = *(const bf16x8*)(bp + 32);
      bf16x8 b2 = *(const bf16x8*)(bp + 64);
      bf16x8 b3 = *(const bf16x8*)(bp + 96);
      #pragma unroll
      for (int rt = 0; rt < 4; ++rt) {
        acc[h][rt] = __builtin_amdgcn_mfma_f32_16x16x32_bf16(afr[rt][0], b0, acc[h][rt], 0, 0, 0);
        acc[h][rt] = __builtin_amdgcn_mfma_f32_16x16x32_bf16(afr[rt][1], b1, acc[h][rt], 0, 0, 0);
        acc[h][rt] = __builtin_amdgcn_mfma_f32_16x16x32_bf16(afr[rt][2], b2, acc[h][rt], 0, 0, 0);
        acc[h][rt] = __builtin_amdgcn_mfma_f32_16x16x32_bf16(afr[rt][3], b3, acc[h][rt], 0, 0, 0);
      }
    }
    __syncthreads();               // all prior LDS reads done (afr on p=0, copies on p>0)
    #pragma unroll
    for (int h = 0; h < 2; ++h) {
      int colp = h * 64 + w * 16 + lr;
      float b = bias[p * 128 + colp];
      #pragma unroll
      for (int rt = 0; rt < 4; ++rt) {
        #pragma unroll
        for (int j = 0; j < 4; ++j) {
          As[(rt * 16 + lk * 4 + j) * 136 + colp] = f2bf(acc[h][rt][j] + b);
        }
      }
    }
    __syncthreads();
    int piece = tid & 15, rbase = tid >> 4;
    #pragma unroll
    for (int it = 0; it < 4; ++it) {  // copy 64x128 tile, 16B/lane coalesced
      int r = rbase + it * 16;
      int grow = row0 + r;
      if (grow < NN) {
        float4 vv = *(const float4*)(&As[r * 136 + piece * 8]);
        *(float4*)(qkv + (size_t)grow * 384 + p * 128 + piece * 8) = vv;
      }
    }
  }
}

// ---------------- K2: Ke = edge_attr @ WeT^T + b_k  (M=E, K=64, Ncols=128), bf16 out ----------------
__global__ __launch_bounds__(256) void k_ke(const float* __restrict__ ea,
                                            const unsigned short* __restrict__ WeT,
                                            const float* __restrict__ bk,
                                            unsigned short* __restrict__ ke) {
  __shared__ unsigned short As[64][72];
  __shared__ unsigned short Bs[64][72];
  int tid = threadIdx.x;
  int row0 = blockIdx.x * 64;
  int col0 = blockIdx.y * 64;
  #pragma unroll
  for (int it = 0; it < 4; ++it) {
    int i4 = tid + it * 256;
    int r = i4 >> 4, c4 = i4 & 15;
    float4 vv = make_float4(0.f, 0.f, 0.f, 0.f);
    int gr = row0 + r;
    if (gr < EE) vv = *(const float4*)(ea + (size_t)gr * 64 + c4 * 4);
    us4 s4 = { f2bf(vv.x), f2bf(vv.y), f2bf(vv.z), f2bf(vv.w) };
    *(us4*)(&As[r][c4 * 4]) = s4;
  }
  #pragma unroll
  for (int it = 0; it < 4; ++it) {
    int i4 = tid + it * 256;
    int r = i4 >> 4, c4 = i4 & 15;
    us4 s4 = *(const us4*)(WeT + (size_t)(col0 + r) * 64 + c4 * 4);
    *(us4*)(&Bs[r][c4 * 4]) = s4;
  }
  __syncthreads();
  int w = tid >> 6, lane = tid & 63, lr = lane & 15, lk = lane >> 4;
  f32x4 acc[4] = {};
  #pragma unroll
  for (int kk = 0; kk < 2; ++kk) {
    int kof = kk * 32 + lk * 8;
    bf16x8 af = *(const bf16x8*)(&As[w * 16 + lr][kof]);
    #pragma unroll
    for (int nt = 0; nt < 4; ++nt) {
      bf16x8 bfrag = *(const bf16x8*)(&Bs[nt * 16 + lr][kof]);
      acc[nt] = __builtin_amdgcn_mfma_f32_16x16x32_bf16(af, bfrag, acc[nt], 0, 0, 0);
    }
  }
  #pragma unroll
  for (int nt = 0; nt < 4; ++nt) {
    int gcol = col0 + nt * 16 + lr;
    float b = bk[gcol];
    #pragma unroll
    for (int j = 0; j < 4; ++j) {
      int grow = row0 + w * 16 + lk * 4 + j;
      if (grow < EE) ke[(size_t)grow * 128 + gcol] = f2bf(acc[nt][j] + b);
    }
  }
}

// ---------------- CSR build: count -> parallel scan -> scatter(pos) ----------------
__global__ void k_count(const int* __restrict__ owners, int* __restrict__ counts) {
  int g = blockIdx.x * 256 + threadIdx.x;
  if (g < GG) atomicAdd(counts + owners[(size_t)g * 4], 1);
}

__global__ __launch_bounds__(256) void k_scan1(const int* __restrict__ counts,
                                               int* __restrict__ lofs,
                                               int* __restrict__ bsums) {
  __shared__ int tmp[256];
  int tid = threadIdx.x;
  int i = blockIdx.x * 256 + tid;
  int v = (i < NN) ? counts[i] : 0;
  tmp[tid] = v;
  __syncthreads();
  int val = v;
  #pragma unroll
  for (int off = 1; off < 256; off <<= 1) {
    int t = (tid >= off) ? tmp[tid - off] : 0;
    __syncthreads();
    val += t;
    tmp[tid] = val;
    __syncthreads();
  }
  if (i < NN) lofs[i] = val - v;
  if (tid == 255) bsums[blockIdx.x] = val;
}

__global__ __launch_bounds__(512) void k_scan2(int* __restrict__ bsums) {
  __shared__ int tmp[512];
  int tid = threadIdx.x;
  int v = (tid < NB) ? bsums[tid] : 0;
  tmp[tid] = v;
  __syncthreads();
  int val = v;
  #pragma unroll
  for (int off = 1; off < 512; off <<= 1) {
    int t = (tid >= off) ? tmp[tid - off] : 0;
    __syncthreads();
    val += t;
    tmp[tid] = val;
    __syncthreads();
  }
  if (tid < NB) bsums[tid] = val - v;
}

__global__ void k_scan3(const int* __restrict__ lofs, const int* __restrict__ bsums,
                        int* __restrict__ starts, int* __restrict__ wcursor) {
  int i = blockIdx.x * 256 + threadIdx.x;
  if (i < NN) {
    int s = lofs[i] + bsums[i >> 8];
    starts[i] = s;
    wcursor[i] = s;
  }
  if (i == 0) starts[NN] = GG;
}

__global__ void k_scatter(const int* __restrict__ owners, int* __restrict__ wcursor,
                          int* __restrict__ pos) {
  int g = blockIdx.x * 256 + threadIdx.x;
  if (g < GG) {
    int v = owners[(size_t)g * 4];
    pos[g] = atomicAdd(wcursor + v, 1);      // CSR slot for this group
  }
}

// ---------------- K3: per-EDGE pass — 16 scores, 4 owner partials, slot writes ----------------
__global__ __launch_bounds__(256) void k_edge(const unsigned short* __restrict__ qkv,
                                              const unsigned short* __restrict__ ke,
                                              const int* __restrict__ pair_u,
                                              const int* __restrict__ pos,
                                              unsigned short* __restrict__ pctx,
                                              float* __restrict__ pden) {
  int e = blockIdx.x * 4 + (threadIdx.x >> 6);
  if (e >= EE) return;
  int lane = threadIdx.x & 63;
  int m[4], ps[4];
  #pragma unroll
  for (int j = 0; j < 4; ++j) {
    m[j]  = __builtin_amdgcn_readfirstlane(pair_u[(size_t)e * 16 + j]);
    ps[j] = __builtin_amdgcn_readfirstlane(pos[(size_t)e * 4 + j]);
  }
  unsigned int kew = *(const unsigned int*)(ke + (size_t)e * 128 + 2 * lane);
  float e0 = bf2f(kew & 0xffffu), e1 = bf2f(kew >> 16);
  float qa[4][2], ka[4][2], va[4][2];
  #pragma unroll
  for (int j = 0; j < 4; ++j) {
    const unsigned short* r = qkv + (size_t)m[j] * 384 + 2 * lane;
    unsigned int qw = *(const unsigned int*)r;
    unsigned int kw = *(const unsigned int*)(r + 128);
    unsigned int vw = *(const unsigned int*)(r + 256);
    qa[j][0] = bf2f(qw & 0xffffu);      qa[j][1] = bf2f(qw >> 16);
    ka[j][0] = bf2f(kw & 0xffffu) + e0; ka[j][1] = bf2f(kw >> 16) + e1;
    va[j][0] = bf2f(vw & 0xffffu);      va[j][1] = bf2f(vw >> 16);
  }
  #pragma unroll
  for (int i = 0; i < 4; ++i) {
    float c0 = 0.f, c1 = 0.f, ds = 0.f;
    #pragma unroll
    for (int j = 0; j < 4; ++j) {
      float sc = qa[i][0] * ka[j][0] + qa[i][1] * ka[j][1];
      sc += __shfl_xor(sc, 1);
      sc += __shfl_xor(sc, 2);
      sc += __shfl_xor(sc, 4);                 // head-local sum (8 lanes/head)
      float ex = __expf(sc);                   // |scores| small: no max-sub pass
      c0 += ex * va[j][0];
      c1 += ex * va[j][1];
      ds += ex;
    }
    unsigned int packed = (unsigned int)f2bf(c0) | ((unsigned int)f2bf(c1) << 16);
    *(unsigned int*)(pctx + (size_t)ps[i] * 128 + 2 * lane) = packed;
    if ((lane & 7) == 0) pden[(size_t)ps[i] * 8 + (lane >> 3)] = ds;
  }
}

// ---------------- K4: out = relu( (sum slots / denom) @ WoT^T + b_o ), f32 out ----------------
__global__ __launch_bounds__(256) void k_out(const unsigned short* __restrict__ pctx,
                                             const float* __restrict__ pden,
                                             const int* __restrict__ starts,
                                             const unsigned short* __restrict__ WoT,
                                             const float* __restrict__ bo,
                                             float* __restrict__ out) {
  __shared__ unsigned short As[64][136];
  __shared__ unsigned short Bs[128][136];
  int tid = threadIdx.x;
  int row0 = blockIdx.x * 64;
  #pragma unroll
  for (int it = 0; it < 8; ++it) {
    int i4 = tid + it * 256;
    int r = i4 >> 5, c4 = i4 & 31;
    int gr = row0 + r;
    float a0 = 0.f, a1 = 0.f, a2 = 0.f, a3 = 0.f, ds = 0.f;
    if (gr < NN) {
      int s0 = starts[gr], s1 = starts[gr + 1];
      for (int sl = s0; sl < s1; ++sl) {
        us4 wv = *(const us4*)(pctx + (size_t)sl * 128 + c4 * 4);
        a0 += bf2f(wv.x); a1 += bf2f(wv.y); a2 += bf2f(wv.z); a3 += bf2f(wv.w);
        ds += pden[(size_t)sl * 8 + (c4 >> 2)];
      }
    }
    float inv = ds > 0.f ? 1.0f / ds : 0.f;
    us4 s4 = { f2bf(a0 * inv), f2bf(a1 * inv), f2bf(a2 * inv), f2bf(a3 * inv) };
    *(us4*)(&As[r][c4 * 4]) = s4;
  }
  #pragma unroll
  for (int it = 0; it < 16; ++it) {
    int i4 = tid + it * 256;
    int r = i4 >> 5, c4 = i4 & 31;
    *(us4*)(&Bs[r][c4 * 4]) = *(const us4*)(WoT + (size_t)r * 128 + c4 * 4);
  }
  __syncthreads();
  int w = tid >> 6, lane = tid & 63, lr = lane & 15, lk = lane >> 4;
  f32x4 acc[8] = {};
  #pragma unroll
  for (int kk = 0; kk < 4; ++kk) {
    int kof = kk * 32 + lk * 8;
    bf16x8 af = *(const bf16x8*)(&As[w * 16 + lr][kof]);
    #pragma unroll
    for (int nt = 0; nt < 8; ++nt) {
      bf16x8 bfrag = *(const bf16x8*)(&Bs[nt * 16 + lr][kof]);
      acc[nt] = __builtin_amdgcn_mfma_f32_16x16x32_bf16(af, bfrag, acc[nt], 0, 0, 0);
    }
  }
  #pragma unroll
  for (int nt = 0; nt < 8; ++nt) {
    int gcol = nt * 16 + lr;
    float b = bo[gcol];
    #pragma unroll
    for (int j = 0; j < 4; ++j) {
      int grow = row0 + w * 16 + lk * 4 + j;
      if (grow < NN) {
        float vvv = acc[nt][j] + b;
        out[(size_t)grow * 128 + gcol] = vvv > 0.f ? vvv : 0.f;
      }
    }
  }
}

extern "C" void kernel_launch(void* const* d_in, const int* in_sizes, int n_in,
                              void* d_out, int out_size, void* d_ws, size_t ws_size,
                              hipStream_t stream) {
  const float* x      = (const float*)d_in[0];
  const float* ea     = (const float*)d_in[1];
  const float* w_lin  = (const float*)d_in[2];
  const float* w_e    = (const float*)d_in[3];
  const float* w_q    = (const float*)d_in[4];
  const float* b_q    = (const float*)d_in[5];
  const float* w_k    = (const float*)d_in[6];
  const float* b_k    = (const float*)d_in[7];
  const float* w_v    = (const float*)d_in[8];
  const float* b_v    = (const float*)d_in[9];
  const float* w_o    = (const float*)d_in[10];
  const float* b_o    = (const float*)d_in[11];
  const int* owners   = (const int*)d_in[12];
  const int* pair_u   = (const int*)d_in[14];
  float* out = (float*)d_out;

  char* base = (char*)d_ws;
  size_t o = 0;
  auto alloc = [&](size_t b) {
    void* p = base + o;
    o = (o + b + 255) & ~(size_t)255;
    return p;
  };
  unsigned short* WT      = (unsigned short*)alloc((size_t)384 * 128 * 2);
  unsigned short* WeT     = (unsigned short*)alloc((size_t)128 * 64 * 2);
  unsigned short* WoT     = (unsigned short*)alloc((size_t)128 * 128 * 2);
  float* bias384          = (float*)alloc(384 * 4);
  float* bkB              = (float*)alloc(128 * 4);
  float* boB              = (float*)alloc(128 * 4);
  unsigned short* qkv     = (unsigned short*)alloc((size_t)NN * 384 * 2);
  unsigned short* keb     = (unsigned short*)alloc((size_t)EE * 128 * 2);
  int* counts             = (int*)alloc((size_t)NN * 4);
  int* starts             = (int*)alloc((size_t)(NN + 1) * 4);
  int* wcursor            = (int*)alloc((size_t)NN * 4);
  int* pos                = (int*)alloc((size_t)GG * 4);
  int* lofs               = (int*)alloc((size_t)NN * 4);
  int* bsums              = (int*)alloc((size_t)NB * 4);
  unsigned short* pctx    = (unsigned short*)alloc((size_t)GG * 128 * 2);
  float* pden             = (float*)alloc((size_t)GG * 8 * 4);

  hipMemsetAsync(counts, 0, (size_t)NN * 4, stream);

  k_prep<<<291, 256, 0, stream>>>(w_lin, w_e, w_q, b_q, w_k, b_k, w_v, b_v, w_o, b_o,
                                  WT, WeT, WoT, bias384, bkB, boB);
  k_qkv<<<1563, 256, 0, stream>>>(x, WT, bias384, qkv);
  k_ke<<<dim3(782, 2), 256, 0, stream>>>(ea, WeT, bkB, keb);
  k_count<<<782, 256, 0, stream>>>(owners, counts);
  k_scan1<<<NB, 256, 0, stream>>>(counts, lofs, bsums);
  k_scan2<<<1, 512, 0, stream>>>(bsums);
  k_scan3<<<NB, 256, 0, stream>>>(lofs, bsums, starts, wcursor);
  k_scatter<<<782, 256, 0, stream>>>(owners, wcursor, pos);
  k_edge<<<12500, 256, 0, stream>>>(qkv, keb, pair_u, pos, pctx, pden);
  k_out<<<1563, 256, 0, stream>>>(pctx, pden, starts, WoT, boB, out);
}